// Round 6
// baseline (320.554 us; speedup 1.0000x reference)
//
#include <hip/hip_runtime.h>

#define T_SEQ 2048
#define NHEAD 16
#define HS 64

typedef __bf16 bf16x8 __attribute__((ext_vector_type(8)));
typedef float f32x4 __attribute__((ext_vector_type(4)));

__device__ __forceinline__ unsigned short f2bf(float f) {
  union { float f; unsigned int u; } v; v.f = f;
  return (unsigned short)((v.u + 0x7fffu + ((v.u >> 16) & 1u)) >> 16);
}
__device__ __forceinline__ float bf2f(unsigned short h) {
  union { unsigned int u; float f; } v; v.u = ((unsigned int)h) << 16;
  return v.f;
}
__device__ __forceinline__ bf16x8 ld_bf8(const unsigned short* p) {
  return *(const bf16x8*)p;
}
__device__ __forceinline__ void st_bf8(unsigned short* p, bf16x8 v) {
  *(bf16x8*)p = v;
}
__device__ __forceinline__ bf16x8 cvt8(float4 a, float4 b) {
  bf16x8 r;
  r[0] = (__bf16)a.x; r[1] = (__bf16)a.y; r[2] = (__bf16)a.z; r[3] = (__bf16)a.w;
  r[4] = (__bf16)b.x; r[5] = (__bf16)b.y; r[6] = (__bf16)b.z; r[7] = (__bf16)b.w;
  return r;
}

// C[m,n] = sum_k A[m,k]*B[n,k];  A:[M,K], B:[N,K] row-major.
// af32/bf32: operand element type is float32 (else bf16).
// mode 0: C row-major [M,N] FLOAT32 (harness output).  mode 1: qkv scatter (N=3072), bf16.
__global__ __launch_bounds__(256, 2) void gemm_bt(
    const void* __restrict__ Av, const void* __restrict__ Bv,
    float* __restrict__ Cout,
    unsigned short* __restrict__ qb, unsigned short* __restrict__ kb,
    unsigned short* __restrict__ vtb,
    int M, int N, int K, int af32, int bf32, int mode) {
  __shared__ unsigned short As[128 * 64];
  __shared__ unsigned short Bs[128 * 64];
  const int tid = threadIdx.x;
  const int wid = tid >> 6, lane = tid & 63;
  const int quad = lane >> 4, l16 = lane & 15;
  const int m0 = blockIdx.y * 128, n0 = blockIdx.x * 128;
  const int wm = (wid >> 1) * 64, wn = (wid & 1) * 64;
  const int row_in = tid >> 3;
  const int col_in = (tid & 7) * 8;
  const float* Agf = (const float*)Av + (size_t)(m0 + row_in) * K + col_in;
  const float* Bgf = (const float*)Bv + (size_t)(n0 + row_in) * K + col_in;
  const unsigned short* Agh = (const unsigned short*)Av + (size_t)(m0 + row_in) * K + col_in;
  const unsigned short* Bgh = (const unsigned short*)Bv + (size_t)(n0 + row_in) * K + col_in;
  f32x4 acc[4][4] = {};
  const int nkt = K >> 6;
  for (int kt = 0; kt < nkt; ++kt) {
    bf16x8 as8[4], bs8[4];
    if (af32) {
      #pragma unroll
      for (int j = 0; j < 4; ++j) {
        const float* p = Agf + (size_t)j * 32 * K + kt * 64;
        as8[j] = cvt8(*(const float4*)p, *(const float4*)(p + 4));
      }
    } else {
      #pragma unroll
      for (int j = 0; j < 4; ++j)
        as8[j] = ld_bf8(Agh + (size_t)j * 32 * K + kt * 64);
    }
    if (bf32) {
      #pragma unroll
      for (int j = 0; j < 4; ++j) {
        const float* p = Bgf + (size_t)j * 32 * K + kt * 64;
        bs8[j] = cvt8(*(const float4*)p, *(const float4*)(p + 4));
      }
    } else {
      #pragma unroll
      for (int j = 0; j < 4; ++j)
        bs8[j] = ld_bf8(Bgh + (size_t)j * 32 * K + kt * 64);
    }
    __syncthreads();
    #pragma unroll
    for (int j = 0; j < 4; ++j) {
      st_bf8(&As[(j * 32 + row_in) * 64 + col_in], as8[j]);
      st_bf8(&Bs[(j * 32 + row_in) * 64 + col_in], bs8[j]);
    }
    __syncthreads();
    #pragma unroll
    for (int ks = 0; ks < 2; ++ks) {
      bf16x8 af[4], bfr[4];
      #pragma unroll
      for (int mt = 0; mt < 4; ++mt)
        af[mt] = ld_bf8(&As[(wm + mt * 16 + l16) * 64 + ks * 32 + quad * 8]);
      #pragma unroll
      for (int nt = 0; nt < 4; ++nt)
        bfr[nt] = ld_bf8(&Bs[(wn + nt * 16 + l16) * 64 + ks * 32 + quad * 8]);
      #pragma unroll
      for (int mt = 0; mt < 4; ++mt)
        #pragma unroll
        for (int nt = 0; nt < 4; ++nt)
          acc[mt][nt] = __builtin_amdgcn_mfma_f32_16x16x32_bf16(af[mt], bfr[nt], acc[mt][nt], 0, 0, 0);
    }
  }
  #pragma unroll
  for (int mt = 0; mt < 4; ++mt) {
    #pragma unroll
    for (int nt = 0; nt < 4; ++nt) {
      const int n = n0 + wn + nt * 16 + l16;
      #pragma unroll
      for (int r = 0; r < 4; ++r) {
        const int m = m0 + wm + mt * 16 + quad * 4 + r;
        if (mode == 0) {
          Cout[(size_t)m * N + n] = acc[mt][nt][r];   // fp32 output
        } else {
          const unsigned short val = f2bf(acc[mt][nt][r]);
          const int b = m >> 11, t = m & (T_SEQ - 1);
          const int which = n >> 10, c = n & 1023;
          const int h = c >> 6, d = c & 63;
          const int bh = b * NHEAD + h;
          if (which == 0)      qb[((size_t)bh * T_SEQ + t) * HS + d] = val;
          else if (which == 1) kb[((size_t)bh * T_SEQ + t) * HS + d] = val;
          else                 vtb[((size_t)bh * HS + d) * T_SEQ + t] = val;  // V transposed
        }
      }
    }
  }
}

// Reference's rolled-RoPE:
//   er[i] = x[2i]*c[i] - x[(2i-1) mod 64]*s[i]
//   ep[i] = x[2i+1]*c[i] + er[(i+1) mod 32]*s[i]
__global__ __launch_bounds__(256, 1) void rope(unsigned short* __restrict__ qb,
                                               unsigned short* __restrict__ kb) {
  const int idx = blockIdx.x * 256 + threadIdx.x;
  unsigned short* buf = (idx < 65536 ? qb : kb) + (size_t)(idx & 65535) * HS;
  const int t = idx & (T_SEQ - 1);
  float x[64];
  #pragma unroll
  for (int j = 0; j < 64; ++j) x[j] = bf2f(buf[j]);
  __asm__ volatile("" ::: "memory");
  float c[32], s[32], er[32];
  #pragma unroll
  for (int i = 0; i < 32; ++i) {
    const float ang = (float)t * exp2f(-0.41524101186092029f * (float)i);
    c[i] = cosf(ang); s[i] = sinf(ang);
  }
  #pragma unroll
  for (int i = 0; i < 32; ++i)
    er[i] = x[2 * i] * c[i] - x[(2 * i + 63) & 63] * s[i];
  #pragma unroll
  for (int i = 0; i < 32; ++i) {
    const float ep = x[2 * i + 1] * c[i] + er[(i + 1) & 31] * s[i];
    buf[2 * i]     = f2bf(er[i]);
    buf[2 * i + 1] = f2bf(ep);
  }
}

// Flash attention. Block = (bh, 64-row q-tile), 4 waves x 16 q-rows.
__global__ __launch_bounds__(256, 2) void attn(
    const unsigned short* __restrict__ qb, const unsigned short* __restrict__ kb,
    const unsigned short* __restrict__ vt, unsigned short* __restrict__ yb) {
  __shared__ unsigned short P[4][16 * 32];
  const int bh = blockIdx.x & 31;
  const int qt = 31 - (blockIdx.x >> 5);
  const int wid = threadIdx.x >> 6, lane = threadIdx.x & 63;
  const int quad = lane >> 4, l16 = lane & 15;
  const int qrow0 = qt * 64 + wid * 16;
  const unsigned short* qptr = qb + ((size_t)bh * T_SEQ + qrow0 + l16) * HS;
  const bf16x8 aq0 = ld_bf8(qptr + quad * 8);
  const bf16x8 aq1 = ld_bf8(qptr + 32 + quad * 8);
  f32x4 O[4] = {};
  float m_i[4], l_i[4], alpha[4];
  #pragma unroll
  for (int r = 0; r < 4; ++r) { m_i[r] = -1e30f; l_i[r] = 0.f; }
  unsigned short* Pw = P[wid];
  const int nkt = qt * 2 + 2;
  for (int kt = 0; kt < nkt; ++kt) {
    const int k0 = kt * 32;
    if (k0 > qrow0 + 15) break;  // wave-uniform causal skip
    const unsigned short* kptr = kb + ((size_t)bh * T_SEQ + k0) * HS;
    const bf16x8 bk00 = ld_bf8(kptr + l16 * HS + quad * 8);
    const bf16x8 bk01 = ld_bf8(kptr + l16 * HS + 32 + quad * 8);
    const bf16x8 bk10 = ld_bf8(kptr + (16 + l16) * HS + quad * 8);
    const bf16x8 bk11 = ld_bf8(kptr + (16 + l16) * HS + 32 + quad * 8);
    f32x4 S0 = {}, S1 = {};
    S0 = __builtin_amdgcn_mfma_f32_16x16x32_bf16(aq0, bk00, S0, 0, 0, 0);
    S0 = __builtin_amdgcn_mfma_f32_16x16x32_bf16(aq1, bk01, S0, 0, 0, 0);
    S1 = __builtin_amdgcn_mfma_f32_16x16x32_bf16(aq0, bk10, S1, 0, 0, 0);
    S1 = __builtin_amdgcn_mfma_f32_16x16x32_bf16(aq1, bk11, S1, 0, 0, 0);
    #pragma unroll
    for (int r = 0; r < 4; ++r) {
      const int row_r = qrow0 + quad * 4 + r;
      const float s0 = (k0 + l16 <= row_r) ? S0[r] * 0.125f : -1e30f;
      const float s1 = (k0 + 16 + l16 <= row_r) ? S1[r] * 0.125f : -1e30f;
      float tm = fmaxf(s0, s1);
      #pragma unroll
      for (int off = 1; off < 16; off <<= 1) tm = fmaxf(tm, __shfl_xor(tm, off, 64));
      const float mnew = fmaxf(fmaxf(m_i[r], tm), -1e30f);
      alpha[r] = __expf(m_i[r] - mnew);
      const unsigned short h0 = f2bf(__expf(s0 - mnew));
      const unsigned short h1 = f2bf(__expf(s1 - mnew));
      float rs = bf2f(h0) + bf2f(h1);           // denominator from ROUNDED P (matches numerator)
      #pragma unroll
      for (int off = 1; off < 16; off <<= 1) rs += __shfl_xor(rs, off, 64);
      l_i[r] = l_i[r] * alpha[r] + rs;
      m_i[r] = mnew;
      Pw[(quad * 4 + r) * 32 + l16] = h0;
      Pw[(quad * 4 + r) * 32 + 16 + l16] = h1;
    }
    #pragma unroll
    for (int vg = 0; vg < 4; ++vg)
      #pragma unroll
      for (int r = 0; r < 4; ++r) O[vg][r] *= alpha[r];
    __asm__ volatile("s_waitcnt lgkmcnt(0)" ::: "memory");
    const bf16x8 pa = ld_bf8(&Pw[l16 * 32 + quad * 8]);
    __asm__ volatile("" ::: "memory");
    const unsigned short* vptr = vt + (size_t)bh * HS * T_SEQ + k0;
    #pragma unroll
    for (int vg = 0; vg < 4; ++vg) {
      const bf16x8 vb = ld_bf8(vptr + (size_t)(vg * 16 + l16) * T_SEQ + quad * 8);
      O[vg] = __builtin_amdgcn_mfma_f32_16x16x32_bf16(pa, vb, O[vg], 0, 0, 0);
    }
  }
  const int b = bh >> 4, h = bh & 15;
  #pragma unroll
  for (int r = 0; r < 4; ++r) {
    const float inv = 1.0f / fmaxf(l_i[r], 1e-30f);
    const int row = qrow0 + quad * 4 + r;
    #pragma unroll
    for (int vg = 0; vg < 4; ++vg)
      yb[((size_t)b * T_SEQ + row) * 1024 + h * HS + vg * 16 + l16] = f2bf(O[vg][r] * inv);
  }
}

extern "C" void kernel_launch(void* const* d_in, const int* in_sizes, int n_in,
                              void* d_out, int out_size, void* d_ws, size_t ws_size,
                              hipStream_t stream) {
  const float* x      = (const float*)d_in[0];   // FP32 inputs per reference
  const float* w_attn = (const float*)d_in[1];
  const float* w_proj = (const float*)d_in[2];
  float* out = (float*)d_out;                    // FP32 output per reference
  unsigned short* qb = (unsigned short*)d_ws;          // [32][2048][64] bf16, 8 MB
  unsigned short* kb = qb + (size_t)4194304;           // 8 MB
  unsigned short* vt = kb + (size_t)4194304;           // [32][64][2048] transposed, 8 MB
  unsigned short* yb = vt + (size_t)4194304;           // [2][2048][1024] bf16, 8 MB

  // 1) qkv = x @ w_attn^T (f32 in, bf16 staged) -> q/k/v layouts
  gemm_bt<<<dim3(24, 32), 256, 0, stream>>>(x, w_attn, nullptr, qb, kb, vt,
                                            4096, 3072, 1024, 1, 1, 1);
  // 2) RoPE in-place on q, k
  rope<<<dim3(512), 256, 0, stream>>>(qb, kb);
  // 3) causal flash attention -> y bf16
  attn<<<dim3(1024), 256, 0, stream>>>(qb, kb, vt, yb);
  // 4) out = y(bf16) @ w_proj^T(f32) -> FLOAT32
  gemm_bt<<<dim3(8, 32), 256, 0, stream>>>(yb, w_proj, out, nullptr, nullptr, nullptr,
                                           4096, 1024, 1024, 0, 1, 0);
}

// Round 8
// 305.828 us; speedup vs baseline: 1.0482x; 1.0482x over previous
//
#include <hip/hip_runtime.h>

#define T_SEQ 2048
#define NHEAD 16
#define HS 64

typedef __bf16 bf16x8 __attribute__((ext_vector_type(8)));
typedef float f32x4 __attribute__((ext_vector_type(4)));

__device__ __forceinline__ unsigned short f2bf(float f) {
  union { float f; unsigned int u; } v; v.f = f;
  return (unsigned short)((v.u + 0x7fffu + ((v.u >> 16) & 1u)) >> 16);
}
__device__ __forceinline__ float bf2f(unsigned short h) {
  union { unsigned int u; float f; } v; v.u = ((unsigned int)h) << 16;
  return v.f;
}
__device__ __forceinline__ bf16x8 ld_bf8(const unsigned short* p) {
  return *(const bf16x8*)p;
}
__device__ __forceinline__ void st_bf8(unsigned short* p, bf16x8 v) {
  *(bf16x8*)p = v;
}
__device__ __forceinline__ bf16x8 cvt8(float4 a, float4 b) {
  bf16x8 r;
  r[0] = (__bf16)a.x; r[1] = (__bf16)a.y; r[2] = (__bf16)a.z; r[3] = (__bf16)a.w;
  r[4] = (__bf16)b.x; r[5] = (__bf16)b.y; r[6] = (__bf16)b.z; r[7] = (__bf16)b.w;
  return r;
}

// C[m,n] = sum_k A[m,k]*B[n,k];  A:[M,K], B:[N,K] row-major.
// af32/bf32: operand element type is float32 (else bf16).
// mode 0: C row-major [M,N] FLOAT32 (harness output).  mode 1: qkv scatter (N=3072), bf16.
__global__ __launch_bounds__(256, 2) void gemm_bt(
    const void* __restrict__ Av, const void* __restrict__ Bv,
    float* __restrict__ Cout,
    unsigned short* __restrict__ qb, unsigned short* __restrict__ kb,
    unsigned short* __restrict__ vtb,
    int M, int N, int K, int af32, int bf32, int mode) {
  __shared__ unsigned short As[128 * 64];
  __shared__ unsigned short Bs[128 * 64];
  const int tid = threadIdx.x;
  const int wid = tid >> 6, lane = tid & 63;
  const int quad = lane >> 4, l16 = lane & 15;
  const int m0 = blockIdx.y * 128, n0 = blockIdx.x * 128;
  const int wm = (wid >> 1) * 64, wn = (wid & 1) * 64;
  const int row_in = tid >> 3;
  const int col_in = (tid & 7) * 8;
  const float* Agf = (const float*)Av + (size_t)(m0 + row_in) * K + col_in;
  const float* Bgf = (const float*)Bv + (size_t)(n0 + row_in) * K + col_in;
  const unsigned short* Agh = (const unsigned short*)Av + (size_t)(m0 + row_in) * K + col_in;
  const unsigned short* Bgh = (const unsigned short*)Bv + (size_t)(n0 + row_in) * K + col_in;
  f32x4 acc[4][4] = {};
  const int nkt = K >> 6;
  for (int kt = 0; kt < nkt; ++kt) {
    bf16x8 as8[4], bs8[4];
    if (af32) {
      #pragma unroll
      for (int j = 0; j < 4; ++j) {
        const float* p = Agf + (size_t)j * 32 * K + kt * 64;
        as8[j] = cvt8(*(const float4*)p, *(const float4*)(p + 4));
      }
    } else {
      #pragma unroll
      for (int j = 0; j < 4; ++j)
        as8[j] = ld_bf8(Agh + (size_t)j * 32 * K + kt * 64);
    }
    if (bf32) {
      #pragma unroll
      for (int j = 0; j < 4; ++j) {
        const float* p = Bgf + (size_t)j * 32 * K + kt * 64;
        bs8[j] = cvt8(*(const float4*)p, *(const float4*)(p + 4));
      }
    } else {
      #pragma unroll
      for (int j = 0; j < 4; ++j)
        bs8[j] = ld_bf8(Bgh + (size_t)j * 32 * K + kt * 64);
    }
    __syncthreads();
    #pragma unroll
    for (int j = 0; j < 4; ++j) {
      st_bf8(&As[(j * 32 + row_in) * 64 + col_in], as8[j]);
      st_bf8(&Bs[(j * 32 + row_in) * 64 + col_in], bs8[j]);
    }
    __syncthreads();
    #pragma unroll
    for (int ks = 0; ks < 2; ++ks) {
      bf16x8 af[4], bfr[4];
      #pragma unroll
      for (int mt = 0; mt < 4; ++mt)
        af[mt] = ld_bf8(&As[(wm + mt * 16 + l16) * 64 + ks * 32 + quad * 8]);
      #pragma unroll
      for (int nt = 0; nt < 4; ++nt)
        bfr[nt] = ld_bf8(&Bs[(wn + nt * 16 + l16) * 64 + ks * 32 + quad * 8]);
      #pragma unroll
      for (int mt = 0; mt < 4; ++mt)
        #pragma unroll
        for (int nt = 0; nt < 4; ++nt)
          acc[mt][nt] = __builtin_amdgcn_mfma_f32_16x16x32_bf16(af[mt], bfr[nt], acc[mt][nt], 0, 0, 0);
    }
  }
  #pragma unroll
  for (int mt = 0; mt < 4; ++mt) {
    #pragma unroll
    for (int nt = 0; nt < 4; ++nt) {
      const int n = n0 + wn + nt * 16 + l16;
      #pragma unroll
      for (int r = 0; r < 4; ++r) {
        const int m = m0 + wm + mt * 16 + quad * 4 + r;
        if (mode == 0) {
          Cout[(size_t)m * N + n] = acc[mt][nt][r];   // fp32 output
        } else {
          const unsigned short val = f2bf(acc[mt][nt][r]);
          const int b = m >> 11, t = m & (T_SEQ - 1);
          const int which = n >> 10, c = n & 1023;
          const int h = c >> 6, d = c & 63;
          const int bh = b * NHEAD + h;
          if (which == 0)      qb[((size_t)bh * T_SEQ + t) * HS + d] = val;
          else if (which == 1) kb[((size_t)bh * T_SEQ + t) * HS + d] = val;
          else                 vtb[((size_t)bh * HS + d) * T_SEQ + t] = val;  // V transposed
        }
      }
    }
  }
}

// Reference's rolled-RoPE:
//   er[i] = x[2i]*c[i] - x[(2i-1) mod 64]*s[i]
//   ep[i] = x[2i+1]*c[i] + er[(i+1) mod 32]*s[i]
__global__ __launch_bounds__(256, 1) void rope(unsigned short* __restrict__ qb,
                                               unsigned short* __restrict__ kb) {
  const int idx = blockIdx.x * 256 + threadIdx.x;
  unsigned short* buf = (idx < 65536 ? qb : kb) + (size_t)(idx & 65535) * HS;
  const int t = idx & (T_SEQ - 1);
  float x[64];
  #pragma unroll
  for (int j = 0; j < 64; ++j) x[j] = bf2f(buf[j]);
  __asm__ volatile("" ::: "memory");
  float c[32], s[32], er[32];
  #pragma unroll
  for (int i = 0; i < 32; ++i) {
    const float ang = (float)t * exp2f(-0.41524101186092029f * (float)i);
    c[i] = cosf(ang); s[i] = sinf(ang);
  }
  #pragma unroll
  for (int i = 0; i < 32; ++i)
    er[i] = x[2 * i] * c[i] - x[(2 * i + 63) & 63] * s[i];
  #pragma unroll
  for (int i = 0; i < 32; ++i) {
    const float ep = x[2 * i + 1] * c[i] + er[(i + 1) & 31] * s[i];
    buf[2 * i]     = f2bf(er[i]);
    buf[2 * i + 1] = f2bf(ep);
  }
}

// Flash attention v2: ONE WAVE per block (64 thr), 16 q-rows per wave.
// Grid = 4096 units sorted longest-first (round-robin balances CUs).
// 64-wide K passes: 8 QK MFMA + 8 PV MFMA per pass; V loads issued before softmax.
// P via per-wave LDS tile, padded stride 72 (conflict-reduced), typed __bf16.
__global__ __launch_bounds__(64) void attn(
    const unsigned short* __restrict__ qb, const unsigned short* __restrict__ kb,
    const unsigned short* __restrict__ vt, unsigned short* __restrict__ yb) {
  __shared__ __bf16 Pl[16][72];
  const int u = blockIdx.x;            // 0..4095
  const int qi = 127 - (u >> 5);       // q-tile 0..127, longest first
  const int bh = u & 31;
  const int q0 = qi * 16;
  const int lane = threadIdx.x & 63;
  const int quad = lane >> 4, l16 = lane & 15;

  const unsigned short* qptr = qb + ((size_t)bh * T_SEQ + q0 + l16) * HS;
  const bf16x8 aq0 = ld_bf8(qptr + quad * 8);        // A-frag kk 0..31
  const bf16x8 aq1 = ld_bf8(qptr + 32 + quad * 8);   // A-frag kk 32..63
  f32x4 O[4] = {};
  float m_i[4], l_i[4], alpha[4];
  #pragma unroll
  for (int r = 0; r < 4; ++r) { m_i[r] = -1e30f; l_i[r] = 0.f; }

  const unsigned short* kbase = kb + (size_t)bh * T_SEQ * HS;
  const unsigned short* vbase = vt + (size_t)bh * HS * T_SEQ;
  const int kend = q0 + 15;

  for (int k0 = 0; k0 <= kend; k0 += 64) {
    // K B-frags: 4 S-tiles x 2 kk-chunks
    bf16x8 bk[4][2];
    #pragma unroll
    for (int t = 0; t < 4; ++t) {
      const unsigned short* kp = kbase + (size_t)(k0 + t * 16 + l16) * HS;
      bk[t][0] = ld_bf8(kp + quad * 8);
      bk[t][1] = ld_bf8(kp + 32 + quad * 8);
    }
    f32x4 S[4] = {};
    #pragma unroll
    for (int t = 0; t < 4; ++t) {
      S[t] = __builtin_amdgcn_mfma_f32_16x16x32_bf16(aq0, bk[t][0], S[t], 0, 0, 0);
      S[t] = __builtin_amdgcn_mfma_f32_16x16x32_bf16(aq1, bk[t][1], S[t], 0, 0, 0);
    }
    // V B-frags for both kk-chunks: issue now, consumed after softmax.
    bf16x8 vb[2][4];
    #pragma unroll
    for (int c = 0; c < 2; ++c)
      #pragma unroll
      for (int vg = 0; vg < 4; ++vg)
        vb[c][vg] = ld_bf8(vbase + (size_t)(vg * 16 + l16) * T_SEQ + k0 + c * 32 + quad * 8);
    // online softmax over 64 k-cols, 4 q-rows per lane (quad*4+r)
    #pragma unroll
    for (int r = 0; r < 4; ++r) {
      const int row = q0 + quad * 4 + r;
      float s[4];
      #pragma unroll
      for (int t = 0; t < 4; ++t)
        s[t] = (k0 + t * 16 + l16 <= row) ? S[t][r] * 0.125f : -1e30f;
      float tm = fmaxf(fmaxf(s[0], s[1]), fmaxf(s[2], s[3]));
      #pragma unroll
      for (int off = 1; off < 16; off <<= 1) tm = fmaxf(tm, __shfl_xor(tm, off, 64));
      const float mnew = fmaxf(m_i[r], tm);
      alpha[r] = __expf(m_i[r] - mnew);
      unsigned short h[4];
      float rs = 0.f;
      #pragma unroll
      for (int t = 0; t < 4; ++t) {
        h[t] = f2bf(__expf(s[t] - mnew));
        rs += bf2f(h[t]);                 // rounded-P denominator (matches numerator)
      }
      #pragma unroll
      for (int off = 1; off < 16; off <<= 1) rs += __shfl_xor(rs, off, 64);
      l_i[r] = l_i[r] * alpha[r] + rs;
      m_i[r] = mnew;
      #pragma unroll
      for (int t = 0; t < 4; ++t)
        Pl[quad * 4 + r][t * 16 + l16] = __builtin_bit_cast(__bf16, h[t]);   // typed store
    }
    #pragma unroll
    for (int vg = 0; vg < 4; ++vg)
      #pragma unroll
      for (int r = 0; r < 4; ++r) O[vg][r] *= alpha[r];
    // P A-frags from LDS (same-wave dependency -> compiler lgkmcnt)
    #pragma unroll
    for (int c = 0; c < 2; ++c) {
      const bf16x8 pa = *(const bf16x8*)&Pl[l16][c * 32 + quad * 8];
      #pragma unroll
      for (int vg = 0; vg < 4; ++vg)
        O[vg] = __builtin_amdgcn_mfma_f32_16x16x32_bf16(pa, vb[c][vg], O[vg], 0, 0, 0);
    }
  }
  const int b = bh >> 4, h = bh & 15;
  #pragma unroll
  for (int r = 0; r < 4; ++r) {
    const float inv = 1.0f / fmaxf(l_i[r], 1e-30f);
    const int row = q0 + quad * 4 + r;
    #pragma unroll
    for (int vg = 0; vg < 4; ++vg)
      yb[((size_t)b * T_SEQ + row) * 1024 + h * HS + vg * 16 + l16] = f2bf(O[vg][r] * inv);
  }
}

extern "C" void kernel_launch(void* const* d_in, const int* in_sizes, int n_in,
                              void* d_out, int out_size, void* d_ws, size_t ws_size,
                              hipStream_t stream) {
  const float* x      = (const float*)d_in[0];   // FP32 inputs per reference
  const float* w_attn = (const float*)d_in[1];
  const float* w_proj = (const float*)d_in[2];
  float* out = (float*)d_out;                    // FP32 output per reference
  unsigned short* qb = (unsigned short*)d_ws;          // [32][2048][64] bf16, 8 MB
  unsigned short* kb = qb + (size_t)4194304;           // 8 MB
  unsigned short* vt = kb + (size_t)4194304;           // [32][64][2048] transposed, 8 MB
  unsigned short* yb = vt + (size_t)4194304;           // [2][2048][1024] bf16, 8 MB

  // 1) qkv = x @ w_attn^T (f32 in, bf16 staged) -> q/k/v layouts
  gemm_bt<<<dim3(24, 32), 256, 0, stream>>>(x, w_attn, nullptr, qb, kb, vt,
                                            4096, 3072, 1024, 1, 1, 1);
  // 2) RoPE in-place on q, k
  rope<<<dim3(512), 256, 0, stream>>>(qb, kb);
  // 3) causal flash attention -> y bf16 (one wave per block, balanced)
  attn<<<dim3(4096), 64, 0, stream>>>(qb, kb, vt, yb);
  // 4) out = y(bf16) @ w_proj^T(f32) -> FLOAT32
  gemm_bt<<<dim3(8, 32), 256, 0, stream>>>(yb, w_proj, out, nullptr, nullptr, nullptr,
                                           4096, 1024, 1024, 0, 1, 0);
}